// Round 1
// baseline (1119.488 us; speedup 1.0000x reference)
//
#include <hip/hip_runtime.h>
#include <stdint.h>

// Problem constants (LinearAttention: B=16, N=4096, C=768, H=12, d=64)
#define BQ     16
#define NSEQ   4096
#define CD     768
#define NH     12
#define DH     64
#define MROWS  (BQ * NSEQ)   // 65536
#define K3C    (3 * CD)      // 2304

typedef __attribute__((ext_vector_type(8))) short      short8;   // 8 bf16 = 4 VGPR (MFMA frag)
typedef __attribute__((ext_vector_type(4))) float      f32x4;    // MFMA accumulator
typedef __attribute__((ext_vector_type(4))) unsigned short us4v;
typedef __attribute__((ext_vector_type(8))) unsigned short us8v;

__device__ __forceinline__ unsigned short f2bf(float f) {
  unsigned int u = __float_as_uint(f);
  return (unsigned short)((u + 0x7FFFu + ((u >> 16) & 1u)) >> 16);  // RNE
}
__device__ __forceinline__ float bf2f(unsigned short s) {
  return __uint_as_float(((unsigned int)s) << 16);
}
__device__ __forceinline__ void gll16(const void* g, void* l) {
  __builtin_amdgcn_global_load_lds(
      (const __attribute__((address_space(1))) unsigned int*)g,
      (__attribute__((address_space(3))) unsigned int*)l, 16, 0, 0);
}

// ---------------------------------------------------------------------------
// K0: convert qkv_w / proj_w fp32 -> bf16, zero kv+ksum accumulators
// ---------------------------------------------------------------------------
__global__ void k_prep(const float* __restrict__ qkv_w, const float* __restrict__ proj_w,
                       unsigned short* __restrict__ wq, unsigned short* __restrict__ wp,
                       float* __restrict__ kvz /* kv then ksum, contiguous */) {
  int i = blockIdx.x * 256 + threadIdx.x;
  int stride = gridDim.x * 256;
  const int NW1 = K3C * CD / 4;                       // 442368
  const int NW2 = CD * CD / 4;                        // 147456
  const int NZ  = (BQ * NH * DH * DH + BQ * NH * DH) / 4;  // 199680
  for (int t = i; t < NW1; t += stride) {
    f32x4 v = ((const f32x4*)qkv_w)[t];
    us4v o; o[0] = f2bf(v[0]); o[1] = f2bf(v[1]); o[2] = f2bf(v[2]); o[3] = f2bf(v[3]);
    ((us4v*)wq)[t] = o;
  }
  for (int t = i; t < NW2; t += stride) {
    f32x4 v = ((const f32x4*)proj_w)[t];
    us4v o; o[0] = f2bf(v[0]); o[1] = f2bf(v[1]); o[2] = f2bf(v[2]); o[3] = f2bf(v[3]);
    ((us4v*)wp)[t] = o;
  }
  f32x4 z = {0.f, 0.f, 0.f, 0.f};
  for (int t = i; t < NZ; t += stride) ((f32x4*)kvz)[t] = z;
}

// ---------------------------------------------------------------------------
// GEMM: C[m,j] = sum_k A[m,k] * Bw[j,k], K=768, 128x128 tile, BK=32, 4 waves.
// EPI==0 (QKV): A = x fp32 (reg-staged -> bf16 LDS), epilogue split q/k/v+relu.
// EPI==1 (proj): A = out_pre bf16 (global_load_lds), epilogue +bias, f32 out.
// ---------------------------------------------------------------------------
template <int EPI>
__launch_bounds__(256)
__global__ void k_gemm(const void* __restrict__ Aptr,
                       const unsigned short* __restrict__ Bw,
                       unsigned short* __restrict__ q_ws,
                       unsigned short* __restrict__ k_ws,
                       unsigned short* __restrict__ v_ws,
                       const float* __restrict__ bias,
                       float* __restrict__ out) {
  __shared__ unsigned short a_lds[2][128 * 32];
  __shared__ unsigned short b_lds[2][128 * 32];
  const int tid  = threadIdx.x;
  const int lane = tid & 63;
  const int wid  = tid >> 6;
  const int wr   = wid >> 1, wc = wid & 1;
  const size_t M0 = (size_t)blockIdx.y * 128;
  const int    N0 = blockIdx.x * 128;

  f32x4 acc[4][4];
#pragma unroll
  for (int i = 0; i < 4; i++)
#pragma unroll
    for (int j = 0; j < 4; j++) acc[i][j] = (f32x4){0.f, 0.f, 0.f, 0.f};

  const int NT = CD / 32;  // 24 K-steps

  // ---- prologue: stage tile 0 into buf 0 ----
  float4 areg[4];
  if constexpr (EPI == 0) {
    const float* A = (const float*)Aptr;
#pragma unroll
    for (int r = 0; r < 4; r++) {
      int c = r * 256 + tid, row = c >> 3, kc = (c & 7) * 4;
      areg[r] = *(const float4*)(A + (M0 + row) * CD + kc);
    }
  }
#pragma unroll
  for (int is = 0; is < 2; is++) {
    void* l = (void*)&b_lds[0][(is * 256 + wid * 64) * 8];
    int cl = is * 256 + wid * 64 + lane;
    int row = cl >> 2, kb = cl & 3;
    gll16(Bw + (size_t)(N0 + row) * CD + kb * 8, l);
  }
  if constexpr (EPI == 0) {
#pragma unroll
    for (int r = 0; r < 4; r++) {
      int c = r * 256 + tid, row = c >> 3, kc = (c & 7) * 4;
      us4v o; o[0] = f2bf(areg[r].x); o[1] = f2bf(areg[r].y);
      o[2] = f2bf(areg[r].z); o[3] = f2bf(areg[r].w);
      *(us4v*)&a_lds[0][row * 32 + kc] = o;
    }
  } else {
    const unsigned short* A = (const unsigned short*)Aptr;
#pragma unroll
    for (int is = 0; is < 2; is++) {
      void* l = (void*)&a_lds[0][(is * 256 + wid * 64) * 8];
      int cl = is * 256 + wid * 64 + lane;
      int row = cl >> 2, kb = cl & 3;
      gll16(A + (M0 + row) * CD + kb * 8, l);
    }
  }
  __syncthreads();

  int cur = 0;
  for (int kt = 0; kt < NT; ++kt) {
    const bool nx = kt < NT - 1;
    // issue next-tile loads early (T14: HBM latency hides under MFMA)
    if (nx) {
      if constexpr (EPI == 0) {
        const float* A = (const float*)Aptr;
#pragma unroll
        for (int r = 0; r < 4; r++) {
          int c = r * 256 + tid, row = c >> 3, kc = (c & 7) * 4;
          areg[r] = *(const float4*)(A + (M0 + row) * CD + (kt + 1) * 32 + kc);
        }
      } else {
        const unsigned short* A = (const unsigned short*)Aptr;
#pragma unroll
        for (int is = 0; is < 2; is++) {
          void* l = (void*)&a_lds[cur ^ 1][(is * 256 + wid * 64) * 8];
          int cl = is * 256 + wid * 64 + lane;
          int row = cl >> 2, kb = cl & 3;
          gll16(A + (M0 + row) * CD + (size_t)(kt + 1) * 32 + kb * 8, l);
        }
      }
#pragma unroll
      for (int is = 0; is < 2; is++) {
        void* l = (void*)&b_lds[cur ^ 1][(is * 256 + wid * 64) * 8];
        int cl = is * 256 + wid * 64 + lane;
        int row = cl >> 2, kb = cl & 3;
        gll16(Bw + (size_t)(N0 + row) * CD + (size_t)(kt + 1) * 32 + kb * 8, l);
      }
    }
    // fragments + MFMA on current buffer
    short8 af[4], bfr[4];
#pragma unroll
    for (int i = 0; i < 4; i++) {
      int row = wr * 64 + i * 16 + (lane & 15);
      af[i] = *(const short8*)&a_lds[cur][row * 32 + (lane >> 4) * 8];
    }
#pragma unroll
    for (int j = 0; j < 4; j++) {
      int row = wc * 64 + j * 16 + (lane & 15);
      bfr[j] = *(const short8*)&b_lds[cur][row * 32 + (lane >> 4) * 8];
    }
#pragma unroll
    for (int i = 0; i < 4; i++)
#pragma unroll
      for (int j = 0; j < 4; j++)
        acc[i][j] = __builtin_amdgcn_mfma_f32_16x16x32_bf16(af[i], bfr[j], acc[i][j], 0, 0, 0);
    // write-late half of A staging
    if constexpr (EPI == 0) {
      if (nx) {
#pragma unroll
        for (int r = 0; r < 4; r++) {
          int c = r * 256 + tid, row = c >> 3, kc = (c & 7) * 4;
          us4v o; o[0] = f2bf(areg[r].x); o[1] = f2bf(areg[r].y);
          o[2] = f2bf(areg[r].z); o[3] = f2bf(areg[r].w);
          *(us4v*)&a_lds[cur ^ 1][row * 32 + kc] = o;
        }
      }
    }
    __syncthreads();
    cur ^= 1;
  }

  // ---- epilogue ----
  const int rq = lane >> 4, c16 = lane & 15;
  if constexpr (EPI == 0) {
    const int seg = N0 / CD;  // BN=128 never straddles a 768 boundary
    unsigned short* outp = seg == 0 ? q_ws : (seg == 1 ? k_ws : v_ws);
    const int nb = N0 - seg * CD;
    const bool do_relu = seg < 2;
#pragma unroll
    for (int i = 0; i < 4; i++)
#pragma unroll
      for (int j = 0; j < 4; j++)
#pragma unroll
        for (int r = 0; r < 4; r++) {
          size_t row = M0 + wr * 64 + i * 16 + rq * 4 + r;
          int col = nb + wc * 64 + j * 16 + c16;
          float v = acc[i][j][r];
          if (do_relu) v = fmaxf(v, 0.f);
          outp[row * CD + col] = f2bf(v);
        }
  } else {
#pragma unroll
    for (int j = 0; j < 4; j++) {
      int col = N0 + wc * 64 + j * 16 + c16;
      float pb = bias[col];
#pragma unroll
      for (int i = 0; i < 4; i++)
#pragma unroll
        for (int r = 0; r < 4; r++) {
          size_t row = M0 + wr * 64 + i * 16 + rq * 4 + r;
          out[row * CD + col] = acc[i][j][r] + pb;
        }
    }
  }
}

// ---------------------------------------------------------------------------
// K2: kv[bh][d][e] = temp[h] * sum_n k[n,d]*v[n,e]; ksum[bh][d] = sum_n k[n,d]
// grid (4, 192): 4-way split over N with fp32 atomics. 256 thr: e=tid&63, dg=tid>>6.
// ---------------------------------------------------------------------------
__global__ void k_kv(const unsigned short* __restrict__ k_ws,
                     const unsigned short* __restrict__ v_ws,
                     const float* __restrict__ temp,
                     float* __restrict__ kv, float* __restrict__ ksum) {
  __shared__ float kl[64 * 64];
  __shared__ float vl[64 * 64];
  const int tid = threadIdx.x;
  const int s = blockIdx.x;   // N-split 0..3
  const int bh = blockIdx.y;  // 0..191
  const int h = bh % NH;
  const int e = tid & 63, dg = tid >> 6;
  float accv[16];
#pragma unroll
  for (int i = 0; i < 16; i++) accv[i] = 0.f;
  float ksr = 0.f;
  const size_t rowbase = ((size_t)(bh / NH) * NSEQ + s * 1024) * CD + h * DH;

  for (int t = 0; t < 16; ++t) {
    __syncthreads();
#pragma unroll
    for (int r = 0; r < 2; r++) {
      int c = r * 256 + tid, row = c >> 3, cc = (c & 7) * 8;
      size_t g = rowbase + (size_t)(t * 64 + row) * CD + cc;
      us8v kk = *(const us8v*)(k_ws + g);
      us8v vv = *(const us8v*)(v_ws + g);
      float* kp = &kl[row * 64 + cc];
      float* vp = &vl[row * 64 + cc];
#pragma unroll
      for (int x = 0; x < 8; x++) { kp[x] = bf2f(kk[x]); vp[x] = bf2f(vv[x]); }
    }
    __syncthreads();
    for (int n = 0; n < 64; ++n) {
      float vv = vl[n * 64 + e];
      const float* kp = &kl[n * 64 + dg * 16];
#pragma unroll
      for (int i = 0; i < 16; i++) accv[i] += kp[i] * vv;
      if (tid < 64) ksr += kl[n * 64 + tid];
    }
  }
  const float tp = temp[h];
#pragma unroll
  for (int i = 0; i < 16; i++)
    atomicAdd(&kv[((size_t)bh * 64 + dg * 16 + i) * 64 + e], accv[i] * tp);
  if (tid < 64) atomicAdd(&ksum[bh * 64 + tid], ksr);
}

// ---------------------------------------------------------------------------
// K3: out_pre[n][e] = (sum_d q[n,d]*kv[d,e]) / max(100, sum_d q[n,d]*ksum[d])
// grid (16, 192), 256 thr, one row per thread. kv via uniform (scalar) loads.
// ---------------------------------------------------------------------------
__global__ void k_out(const unsigned short* __restrict__ q_ws,
                      const float* __restrict__ kv, const float* __restrict__ ksum,
                      unsigned short* __restrict__ out_pre) {
  __shared__ unsigned short ql[256 * 72];  // 72-pad: 16B-aligned rows, spreads banks
  const int tid = threadIdx.x;
  const int nt = blockIdx.x, bh = blockIdx.y;
  const int h = bh % NH;
  const size_t rowg = (size_t)(bh / NH) * NSEQ + nt * 256;
#pragma unroll
  for (int r = 0; r < 8; r++) {
    int c = r * 256 + tid, row = c >> 3, cc = (c & 7) * 8;
    us8v qv = *(const us8v*)(q_ws + (rowg + row) * CD + h * DH + cc);
    *(us8v*)&ql[row * 72 + cc] = qv;
  }
  __syncthreads();
  const float* kvp = kv + (size_t)bh * 4096;
  const float* ksp = ksum + bh * 64;
  float acc[64];
#pragma unroll
  for (int e = 0; e < 64; e++) acc[e] = 0.f;
  float den = 0.f;
  for (int d = 0; d < 64; ++d) {
    float qd = bf2f(ql[tid * 72 + d]);
    den += qd * ksp[d];
    const float* kr = kvp + d * 64;
#pragma unroll
    for (int e = 0; e < 64; e++) acc[e] += qd * kr[e];
  }
  const float inv = 1.0f / fmaxf(den, 100.f);
  const size_t ob = (rowg + tid) * CD + h * DH;
#pragma unroll
  for (int g = 0; g < 8; ++g) {
    us8v o;
#pragma unroll
    for (int x = 0; x < 8; x++) o[x] = f2bf(acc[g * 8 + x] * inv);
    *(us8v*)(out_pre + ob + g * 8) = o;
  }
}

// ---------------------------------------------------------------------------
extern "C" void kernel_launch(void* const* d_in, const int* in_sizes, int n_in,
                              void* d_out, int out_size, void* d_ws, size_t ws_size,
                              hipStream_t stream) {
  const float* x      = (const float*)d_in[0];
  const float* qkv_w  = (const float*)d_in[1];
  const float* proj_w = (const float*)d_in[2];
  const float* proj_b = (const float*)d_in[3];
  const float* temp   = (const float*)d_in[4];

  char* ws = (char*)d_ws;
  size_t o = 0;
  unsigned short* q_ws = (unsigned short*)(ws + o); o += (size_t)MROWS * CD * 2;
  unsigned short* k_ws = (unsigned short*)(ws + o); o += (size_t)MROWS * CD * 2;
  unsigned short* v_ws = (unsigned short*)(ws + o); o += (size_t)MROWS * CD * 2;  // reused as out_pre
  unsigned short* wq   = (unsigned short*)(ws + o); o += (size_t)K3C * CD * 2;
  unsigned short* wp   = (unsigned short*)(ws + o); o += (size_t)CD * CD * 2;
  float* kv            = (float*)(ws + o);          o += (size_t)BQ * NH * DH * DH * 4;
  float* ksum          = (float*)(ws + o);          o += (size_t)BQ * NH * DH * 4;
  // total ~306.7 MB

  k_prep<<<dim3(3084), dim3(256), 0, stream>>>(qkv_w, proj_w, wq, wp, kv);
  k_gemm<0><<<dim3(K3C / 128, MROWS / 128), dim3(256), 0, stream>>>(
      x, wq, q_ws, k_ws, v_ws, nullptr, nullptr);
  k_kv<<<dim3(4, BQ * NH), dim3(256), 0, stream>>>(k_ws, v_ws, temp, kv, ksum);
  k_out<<<dim3(NSEQ / 256, BQ * NH), dim3(256), 0, stream>>>(q_ws, kv, ksum, v_ws);
  k_gemm<1><<<dim3(CD / 128, MROWS / 128), dim3(256), 0, stream>>>(
      v_ws, wp, nullptr, nullptr, nullptr, proj_b, (float*)d_out);
}